// Round 1
// baseline (1129.426 us; speedup 1.0000x reference)
//
#include <hip/hip_runtime.h>
#include <math.h>

#define HWPIX 3136   // 56*56
#define CH    256
#define NB    16
#define IMG   224

// ---------------- Kernel 1: per-pixel Mahalanobis quadratic form ----------------
// grid = 3136 blocks (one per pixel), block = 256 threads = 4 waves.
// Wave w handles rows d in [64w, 64w+64); lane l handles columns c = 4l..4l+3.
// acc[b][c] += M[d][c] * diff[b][d]   (quad is invariant under M transpose)
__global__ void mahal_kernel(const float* __restrict__ inputs,   // [16][3136][256]
                             const float* __restrict__ mean,     // [3136][256]
                             const float* __restrict__ cvar,     // [3136][256][256]
                             float* __restrict__ mask_small)     // [16][3136]
{
    const int p    = blockIdx.x;
    const int tid  = threadIdx.x;
    const int lane = tid & 63;
    const int w    = tid >> 6;

    // diff staged as [c][b] with stride 20 floats (80 B -> 16B aligned rows)
    __shared__ float sdiff[CH * 20];
    __shared__ float sred[4][16];

    const float* mrow_mean = mean + (size_t)p * CH;

    // stage diff[b][c] -> sdiff[c*20 + b]
    {
        float mv = mrow_mean[tid];
        #pragma unroll
        for (int b = 0; b < NB; ++b) {
            float v = inputs[((size_t)b * HWPIX + p) * CH + tid] - mv;
            sdiff[tid * 20 + b] = v;
        }
    }
    __syncthreads();

    const float* M = cvar + (size_t)p * CH * CH;
    const int c4 = lane * 4;

    float4 acc[NB];
    #pragma unroll
    for (int b = 0; b < NB; ++b) acc[b] = make_float4(0.f, 0.f, 0.f, 0.f);

    #pragma unroll 2
    for (int k = 0; k < 64; ++k) {
        const int d = (w << 6) + k;
        const float4 m = *reinterpret_cast<const float4*>(M + (size_t)d * CH + c4);
        const float4* sdv = reinterpret_cast<const float4*>(&sdiff[d * 20]);
        const float4 dv0 = sdv[0];
        const float4 dv1 = sdv[1];
        const float4 dv2 = sdv[2];
        const float4 dv3 = sdv[3];
        const float dvals[16] = {dv0.x, dv0.y, dv0.z, dv0.w,
                                 dv1.x, dv1.y, dv1.z, dv1.w,
                                 dv2.x, dv2.y, dv2.z, dv2.w,
                                 dv3.x, dv3.y, dv3.z, dv3.w};
        #pragma unroll
        for (int b = 0; b < NB; ++b) {
            const float s = dvals[b];
            acc[b].x = fmaf(m.x, s, acc[b].x);
            acc[b].y = fmaf(m.y, s, acc[b].y);
            acc[b].z = fmaf(m.z, s, acc[b].z);
            acc[b].w = fmaf(m.w, s, acc[b].w);
        }
    }

    // epilogue: q[b] = sum_c acc[b][c] * diff[b][c]  (re-read diff coalesced from global)
    const float4 mn = *reinterpret_cast<const float4*>(mrow_mean + c4);
    float q[NB];
    #pragma unroll
    for (int b = 0; b < NB; ++b) {
        const float4 f = *reinterpret_cast<const float4*>(inputs + ((size_t)b * HWPIX + p) * CH + c4);
        const float4 df = make_float4(f.x - mn.x, f.y - mn.y, f.z - mn.z, f.w - mn.w);
        q[b] = acc[b].x * df.x + acc[b].y * df.y + acc[b].z * df.z + acc[b].w * df.w;
    }

    // 64-lane butterfly reduce per b, then cross-wave via LDS
    #pragma unroll
    for (int b = 0; b < NB; ++b) {
        float v = q[b];
        for (int off = 32; off > 0; off >>= 1) v += __shfl_xor(v, off, 64);
        if (lane == 0) sred[w][b] = v;
    }
    __syncthreads();
    if (tid < NB) {
        const float s = sred[0][tid] + sred[1][tid] + sred[2][tid] + sred[3][tid];
        mask_small[(size_t)tid * HWPIX + p] = sqrtf(fmaxf(s, 0.0f));
    }
}

// ---------------- Kernel 2: bilinear resize 56x56 -> 224x224 (jax half-pixel, clamped) ----
__global__ void resize_kernel(const float* __restrict__ small_, float* __restrict__ out)
{
    const int idx = blockIdx.x * 256 + threadIdx.x;     // 16*224*224
    const int b   = idx / (IMG * IMG);
    const int rem = idx % (IMG * IMG);
    const int oy  = rem / IMG;
    const int ox  = rem % IMG;

    float fy = oy * 0.25f - 0.375f;
    float fx = ox * 0.25f - 0.375f;
    fy = fminf(fmaxf(fy, 0.0f), 55.0f);
    fx = fminf(fmaxf(fx, 0.0f), 55.0f);
    int iy0 = min((int)fy, 54);
    int ix0 = min((int)fx, 54);
    const float wy = fy - iy0;
    const float wx = fx - ix0;

    const float* s = small_ + (size_t)b * HWPIX;
    const float v00 = s[iy0 * 56 + ix0];
    const float v01 = s[iy0 * 56 + ix0 + 1];
    const float v10 = s[(iy0 + 1) * 56 + ix0];
    const float v11 = s[(iy0 + 1) * 56 + ix0 + 1];
    const float v0 = v00 + wx * (v01 - v00);
    const float v1 = v10 + wx * (v11 - v10);
    out[idx] = v0 + wy * (v1 - v0);
}

// ---------------- Gaussian weights helper (per-block in LDS) ----------------
__device__ __forceinline__ void setup_gauss(float* g, float* norm, int tid)
{
    if (tid < 33) {
        const int i = tid - 16;
        g[tid] = expf((float)(-(i * i)) / 32.0f);   // 2*sigma^2 = 32
    }
    __syncthreads();
    if (tid == 0) {
        float s = 0.f;
        for (int i = 0; i < 33; ++i) s += g[i];
        *norm = 1.0f / s;
    }
    __syncthreads();
}

// ---------------- Kernel 3: blur along H (y), reflect-101 ----------------
__global__ void blurh_kernel(const float* __restrict__ in, float* __restrict__ out)
{
    __shared__ float g[33];
    __shared__ float norm;
    const int tid = threadIdx.x;
    setup_gauss(g, &norm, tid);

    const int idx = blockIdx.x * 256 + tid;
    const int b   = idx / (IMG * IMG);
    const int rem = idx % (IMG * IMG);
    const int y   = rem / IMG;
    const int x   = rem % IMG;

    const float* src = in + (size_t)b * IMG * IMG;
    float acc = 0.f;
    #pragma unroll
    for (int i = -16; i <= 16; ++i) {
        int yy = y + i;
        yy = yy < 0 ? -yy : (yy > 223 ? 446 - yy : yy);
        acc += g[i + 16] * src[yy * IMG + x];
    }
    out[idx] = acc * norm;
}

// ---------------- Kernel 4: blur along W (x) + write mask + per-batch max ----------------
__global__ void blurw_kernel(const float* __restrict__ in, float* __restrict__ mask_out,
                             float* __restrict__ score)
{
    __shared__ float g[33];
    __shared__ float norm;
    __shared__ float m4[4];
    const int tid = threadIdx.x;
    setup_gauss(g, &norm, tid);

    const int idx = blockIdx.x * 256 + tid;
    const int b   = idx / (IMG * IMG);
    const int rem = idx % (IMG * IMG);
    const int y   = rem / IMG;
    const int x   = rem % IMG;

    const float* src = in + (size_t)b * IMG * IMG;
    float acc = 0.f;
    #pragma unroll
    for (int i = -16; i <= 16; ++i) {
        int xx = x + i;
        xx = xx < 0 ? -xx : (xx > 223 ? 446 - xx : xx);
        acc += g[i + 16] * src[y * IMG + xx];
    }
    acc *= norm;
    mask_out[idx] = acc;

    // block max (all 256 idx in a block share the same b: 50176 = 196*256)
    float v = acc;
    for (int off = 32; off > 0; off >>= 1) v = fmaxf(v, __shfl_xor(v, off, 64));
    const int lane = tid & 63;
    const int w    = tid >> 6;
    if (lane == 0) m4[w] = v;
    __syncthreads();
    if (tid == 0) {
        const float mm = fmaxf(fmaxf(m4[0], m4[1]), fmaxf(m4[2], m4[3]));
        atomicMax(reinterpret_cast<int*>(score) + b, __float_as_int(mm));  // values >= 0
    }
}

// ---------------- Kernel 0: init score to 0 (d_out is poisoned 0xAA) ----------------
__global__ void init_score(float* __restrict__ score)
{
    if (threadIdx.x < NB) score[threadIdx.x] = 0.0f;
}

extern "C" void kernel_launch(void* const* d_in, const int* in_sizes, int n_in,
                              void* d_out, int out_size, void* d_ws, size_t ws_size,
                              hipStream_t stream)
{
    const float* inputs = (const float*)d_in[0];   // [16][3136][256]
    const float* mean   = (const float*)d_in[1];   // [3136][256]
    const float* cvar   = (const float*)d_in[2];   // [3136][256][256]

    float* score    = (float*)d_out;               // [16]
    float* mask_out = (float*)d_out + NB;          // [16][224][224]

    char* ws = (char*)d_ws;
    float* mask_small = (float*)ws;                                       // 16*3136
    float* resized    = (float*)(ws + (size_t)NB * HWPIX * 4);            // 16*224*224
    float* tmp        = (float*)(ws + (size_t)NB * HWPIX * 4
                                    + (size_t)NB * IMG * IMG * 4);        // 16*224*224

    mahal_kernel <<<HWPIX, 256, 0, stream>>>(inputs, mean, cvar, mask_small);
    resize_kernel<<<(NB * IMG * IMG) / 256, 256, 0, stream>>>(mask_small, resized);
    blurh_kernel <<<(NB * IMG * IMG) / 256, 256, 0, stream>>>(resized, tmp);
    init_score   <<<1, 64, 0, stream>>>(score);
    blurw_kernel <<<(NB * IMG * IMG) / 256, 256, 0, stream>>>(tmp, mask_out, score);
}